// Round 7
// baseline (109.426 us; speedup 1.0000x reference)
//
#include <hip/hip_runtime.h>
#include <stdint.h>

#define HEADS 32
#define HW_N 1024
#define QS 0.36067376022224085f   // 0.25 * log2(e)
#define LOG2E 1.4426950408889634f

typedef __attribute__((ext_vector_type(8))) __bf16 bf16x8;
typedef __attribute__((ext_vector_type(4))) float f32x4;
typedef __attribute__((ext_vector_type(16))) float f32x16;
typedef __attribute__((ext_vector_type(4))) uint32_t u32x4;

__device__ __forceinline__ float b2f(uint16_t u) {
  union { uint32_t i; float f; } v; v.i = ((uint32_t)u) << 16; return v.f;
}
__device__ __forceinline__ uint16_t f2b(float f) {
  uint32_t u = __builtin_bit_cast(uint32_t, f);
  return (uint16_t)((u + 0x7FFFu + ((u >> 16) & 1u)) >> 16);
}

#define GLD16(g, s) __builtin_amdgcn_global_load_lds( \
    (const __attribute__((address_space(1))) void*)(g), \
    (__attribute__((address_space(3))) void*)(s), 16, 0, 0)

// ---------------- prep: f32->bf16 converts + bf16 bias tiles in MFMA C-layout ----------------
__global__ __launch_bounds__(256) void prep(const float* __restrict__ x,
                                            const float* __restrict__ wqv,
                                            const float* __restrict__ pw,
                                            const float* __restrict__ abias,
                                            uint16_t* __restrict__ xb,
                                            uint16_t* __restrict__ wqb,
                                            uint16_t* __restrict__ pwb,
                                            uint16_t* __restrict__ bt2b) {
  const int blk = blockIdx.x;
  const int tid = threadIdx.x;
  if (blk < 3584) {
    const float* in; uint16_t* out; int i;
    if (blk < 2048)      { in = x;   out = xb;  i = blk * 256 + tid; }
    else if (blk < 3072) { in = wqv; out = wqb; i = (blk - 2048) * 256 + tid; }
    else                 { in = pw;  out = pwb; i = (blk - 3072) * 256 + tid; }
    float4 v = ((const float4*)in)[i];
    ushort4 o;
    o.x = f2b(v.x); o.y = f2b(v.y); o.z = f2b(v.z); o.w = f2b(v.w);
    ((ushort4*)out)[i] = o;
  } else {
    const int blk2 = blk - 3584;           // 0..2015
    const int h = blk2 / 63, d31 = blk2 - h * 63;
    const size_t tb = ((size_t)(h * 63 + d31)) << 10;
#pragma unroll
    for (int c = 0; c < 4; ++c) {
      const int idx = c * 256 + tid;       // lane*16 + r
      const int lane = idx >> 4, r = idx & 15;
      const int hi = lane >> 5, ln = lane & 31;
      const int crow = (r & 3) + 8 * (r >> 2) + 4 * hi;
      const int col = 31 + ln - crow;      // 0..62
      bt2b[tb + idx] = f2b(LOG2E * abias[(size_t)(d31 * 63 + col) * 32 + h]);
    }
  }
}

// ---------------- QKV projection GEMM: [4096,512] x [2048,512]^T ----------------
__global__ __launch_bounds__(256) void gemm_qkv(
    const uint16_t* __restrict__ Aop, const uint16_t* __restrict__ Bop,
    uint16_t* __restrict__ qT, uint16_t* __restrict__ ko, uint16_t* __restrict__ vo) {
  const int K = 512;
  __shared__ uint16_t As[2][128 * 32];
  __shared__ uint16_t Bs[2][128 * 32];
  const int tid = threadIdx.x;
  const int lane = tid & 63;
  const int wave = tid >> 6;
  const int am0 = blockIdx.y * 128;
  const int bn0 = blockIdx.x * 128;
  const int m_off = (wave >> 1) * 64;
  const int n_off = (wave & 1) * 64;
  const int sr = tid >> 2;
  const int sc = (tid & 3) << 3;

  auto stage = [&](int buf, int kt) {
    const int k0 = kt << 5;
    GLD16(Aop + (size_t)(am0 + sr) * K + (k0 + sc), &As[buf][tid * 8]);
    GLD16(Aop + (size_t)(am0 + sr + 64) * K + (k0 + sc), &As[buf][(tid + 256) * 8]);
    GLD16(Bop + (size_t)(bn0 + sr) * K + (k0 + sc), &Bs[buf][tid * 8]);
    GLD16(Bop + (size_t)(bn0 + sr + 64) * K + (k0 + sc), &Bs[buf][(tid + 256) * 8]);
  };

  f32x4 acc[4][4] = {};
  stage(0, 0);
  asm volatile("s_waitcnt vmcnt(0)" ::: "memory");
  __syncthreads();

  const int fr = lane & 15;
  const int fk = (lane >> 4) << 3;
  int cur = 0;
  for (int kt = 0; kt < 16; ++kt) {
    if (kt + 1 < 16) stage(cur ^ 1, kt + 1);
    bf16x8 af[4], bf_[4];
#pragma unroll
    for (int mi = 0; mi < 4; ++mi)
      af[mi] = *(const bf16x8*)&As[cur][(m_off + mi * 16 + fr) * 32 + fk];
#pragma unroll
    for (int ni = 0; ni < 4; ++ni)
      bf_[ni] = *(const bf16x8*)&Bs[cur][(n_off + ni * 16 + fr) * 32 + fk];
#pragma unroll
    for (int mi = 0; mi < 4; ++mi)
#pragma unroll
      for (int ni = 0; ni < 4; ++ni)
        acc[mi][ni] = __builtin_amdgcn_mfma_f32_16x16x32_bf16(af[mi], bf_[ni], acc[mi][ni], 0, 0, 0);
    asm volatile("s_waitcnt vmcnt(0)" ::: "memory");
    __syncthreads();
    cur ^= 1;
  }

  const int rb = (lane >> 4) << 2;
  const int cl = lane & 15;
  const int b = am0 >> 10;
  const int h = (bn0 + n_off) >> 6;
  const int bh = b * 32 + h;
#pragma unroll
  for (int mi = 0; mi < 4; ++mi) {
    const int n0 = (am0 & 1023) + m_off + mi * 16 + rb;
    {  // q: transposed + pre-scaled, packed along rows
      ushort4 o;
      o.x = f2b(acc[mi][0][0] * QS); o.y = f2b(acc[mi][0][1] * QS);
      o.z = f2b(acc[mi][0][2] * QS); o.w = f2b(acc[mi][0][3] * QS);
      *(ushort4*)&qT[((size_t)(bh * 16 + cl) << 10) + n0] = o;
    }
#pragma unroll
    for (int r = 0; r < 4; ++r)  // k: row-major
      ko[((size_t)(bh * 1024 + n0 + r)) * 16 + cl] = f2b(acc[mi][1][r]);
#pragma unroll
    for (int nv = 2; nv < 4; ++nv) {  // v: channel-major (V^T), packed
      const int l = h * 32 + (nv - 2) * 16 + cl;
      ushort4 o;
      o.x = f2b(acc[mi][nv][0]); o.y = f2b(acc[mi][nv][1]);
      o.z = f2b(acc[mi][nv][2]); o.w = f2b(acc[mi][nv][3]);
      *(ushort4*)&vo[((size_t)(b * 1024 + l) << 10) + n0] = o;
    }
  }
}

// ---------------- depthwise 3x3 conv (SAME), channel-major in AND out ----------------
__global__ __launch_bounds__(256) void dwconv3x3(const uint16_t* __restrict__ vimg,
                                                 const float* __restrict__ kw,
                                                 uint16_t* __restrict__ vcv) {
  __shared__ float t[1024];
  const int bl = blockIdx.x;  // b*1024 + l
  const int l = bl & 1023;
  const int tid = threadIdx.x;
  const uint16_t* src = vimg + (size_t)bl * 1024;
  {
    uint2 vv = ((const uint2*)src)[tid];
    t[tid * 4 + 0] = b2f((uint16_t)vv.x);
    t[tid * 4 + 1] = b2f((uint16_t)(vv.x >> 16));
    t[tid * 4 + 2] = b2f((uint16_t)vv.y);
    t[tid * 4 + 3] = b2f((uint16_t)(vv.y >> 16));
  }
  float w[9];
#pragma unroll
  for (int i = 0; i < 9; ++i) w[i] = kw[l * 9 + i];
  __syncthreads();
  uint16_t* dst = vcv + (size_t)bl * 1024;
#pragma unroll
  for (int i = 0; i < 4; ++i) {
    const int p = tid + i * 256;
    const int y = p >> 5, x = p & 31;
    float a = 0.f;
#pragma unroll
    for (int dy = 0; dy < 3; ++dy) {
      const int yy = y + dy - 1;
      if (yy < 0 || yy > 31) continue;
#pragma unroll
      for (int dx = 0; dx < 3; ++dx) {
        const int xx = x + dx - 1;
        if (xx < 0 || xx > 31) continue;
        a += t[yy * 32 + xx] * w[dy * 3 + dx];
      }
    }
    dst[p] = f2b(a);
  }
}

// ---------------- MFMA fused attention + hardswish ----------------
// Swapped QK^T with bf16 bias tiles as MFMA C-operand; ping-pong ILP2
// (no register rotation); v_perm pack; permlane32_swap exchange.
// Swap operand order (w0 first) verified-by-elimination: with (w2,w0) both
// candidate HW semantics produce the half-swapped (failed) arrangement; with
// (w0,w2) both produce the round-5 shfl-verified arrangement.
__global__ __launch_bounds__(256) void attn_mfma(
    const uint16_t* __restrict__ qT, const uint16_t* __restrict__ kb,
    const uint16_t* __restrict__ vt, const uint16_t* __restrict__ bt2b,
    uint16_t* __restrict__ hsO) {
  __shared__ float inv_s[128];
  const int blk = blockIdx.x;
  const int bh = blk & 127;   // qt in high bits: 8 sibling blocks share (b,h)
  const int qt = blk >> 7;
  const int b = bh >> 5, h = bh & 31;
  const int tid = threadIdx.x;
  const int lane = tid & 63, wave = tid >> 6;
  const int hi = lane >> 5, ln = lane & 31;

  const int q0 = qt * 128 + wave * 32;
  const int qi = qt * 4 + wave;

  union { ushort u[8]; bf16x8 v; } qu;
#pragma unroll
  for (int j = 0; j < 8; ++j)
    qu.u[j] = qT[((size_t)(bh * 16 + hi * 8 + j) << 10) + q0 + ln];
  const bf16x8 qf = qu.v;

  const uint16_t* kp = kb + ((size_t)bh * 1024 + ln) * 16 + hi * 8;
  const uint16_t* vp = vt + ((size_t)(b * 1024 + h * 32 + ln) << 10) + hi * 8;
  const uint16_t* bp = bt2b + ((size_t)(h * 63 + qi + 31) << 10) + lane * 16;

  f32x16 oa0 = {}, oa1 = {};
  float ls0 = 0.f, ls1 = 0.f, ls2 = 0.f, ls3 = 0.f;

#define LOADSET(off, kf, v0, v1, ca, cb) do {                         \
    kf = *(const bf16x8*)(kp + (off) * 512);                          \
    v0 = *(const bf16x8*)(vp + (off) * 32);                           \
    v1 = *(const bf16x8*)(vp + (off) * 32 + 16);                      \
    ca = *(const u32x4*)(bp - (off) * 1024);                          \
    cb = *(const u32x4*)(bp - (off) * 1024 + 8);                      \
  } while (0)

#define COMPUTE(kf, vf0, vf1, ca, cb, oacc, lsA, lsB) do {            \
    f32x16 cc;                                                        \
    _Pragma("unroll")                                                 \
    for (int j = 0; j < 4; ++j) {                                     \
      const uint32_t ua = ca[j], ub = cb[j];                          \
      cc[2 * j]     = __builtin_bit_cast(float, ua << 16);            \
      cc[2 * j + 1] = __builtin_bit_cast(float, ua & 0xFFFF0000u);    \
      cc[8 + 2 * j]     = __builtin_bit_cast(float, ub << 16);        \
      cc[8 + 2 * j + 1] = __builtin_bit_cast(float, ub & 0xFFFF0000u);\
    }                                                                 \
    const f32x16 s = __builtin_amdgcn_mfma_f32_32x32x16_bf16(kf, qf, cc, 0, 0, 0); \
    float p[16];                                                      \
    _Pragma("unroll")                                                 \
    for (int r = 0; r < 16; ++r) p[r] = __builtin_amdgcn_exp2f(s[r]); \
    _Pragma("unroll")                                                 \
    for (int r = 0; r < 8; ++r) { lsA += p[r]; lsB += p[r + 8]; }     \
    uint32_t w0, w1, w2, w3, w4, w5, w6, w7;                          \
    w0 = __builtin_amdgcn_perm(__builtin_bit_cast(uint32_t, p[1]),  __builtin_bit_cast(uint32_t, p[0]),  0x07060302u); \
    w1 = __builtin_amdgcn_perm(__builtin_bit_cast(uint32_t, p[3]),  __builtin_bit_cast(uint32_t, p[2]),  0x07060302u); \
    w2 = __builtin_amdgcn_perm(__builtin_bit_cast(uint32_t, p[5]),  __builtin_bit_cast(uint32_t, p[4]),  0x07060302u); \
    w3 = __builtin_amdgcn_perm(__builtin_bit_cast(uint32_t, p[7]),  __builtin_bit_cast(uint32_t, p[6]),  0x07060302u); \
    w4 = __builtin_amdgcn_perm(__builtin_bit_cast(uint32_t, p[9]),  __builtin_bit_cast(uint32_t, p[8]),  0x07060302u); \
    w5 = __builtin_amdgcn_perm(__builtin_bit_cast(uint32_t, p[11]), __builtin_bit_cast(uint32_t, p[10]), 0x07060302u); \
    w6 = __builtin_amdgcn_perm(__builtin_bit_cast(uint32_t, p[13]), __builtin_bit_cast(uint32_t, p[12]), 0x07060302u); \
    w7 = __builtin_amdgcn_perm(__builtin_bit_cast(uint32_t, p[15]), __builtin_bit_cast(uint32_t, p[14]), 0x07060302u); \
    asm("v_permlane32_swap_b32 %0, %1" : "+v"(w0), "+v"(w2));         \
    asm("v_permlane32_swap_b32 %0, %1" : "+v"(w1), "+v"(w3));         \
    asm("v_permlane32_swap_b32 %0, %1" : "+v"(w4), "+v"(w6));         \
    asm("v_permlane32_swap_b32 %0, %1" : "+v"(w5), "+v"(w7));         \
    const u32x4 a0u = {w0, w1, w2, w3};                               \
    const u32x4 a1u = {w4, w5, w6, w7};                               \
    oacc = __builtin_amdgcn_mfma_f32_32x32x16_bf16(                   \
        __builtin_bit_cast(bf16x8, a0u), vf0, oacc, 0, 0, 0);         \
    oacc = __builtin_amdgcn_mfma_f32_32x32x16_bf16(                   \
        __builtin_bit_cast(bf16x8, a1u), vf1, oacc, 0, 0, 0);         \
  } while (0)

  bf16x8 kA, vA0, vA1, kB, vB0, vB1;
  u32x4 cA0, cA1, cB0, cB1;
  LOADSET(0, kA, vA0, vA1, cA0, cA1);
  for (int t = 0; t < 16; ++t) {
    LOADSET(1, kB, vB0, vB1, cB0, cB1);          // tile 2t+1
    COMPUTE(kA, vA0, vA1, cA0, cA1, oa0, ls0, ls1);  // tile 2t
    kp += 1024; vp += 64; bp -= 2048;            // advance 2 tiles
    LOADSET(0, kA, vA0, vA1, cA0, cA1);          // tile 2t+2 (last iter: harmless ws read)
    COMPUTE(kB, vB0, vB1, cB0, cB1, oa1, ls2, ls3);  // tile 2t+1
  }
#undef LOADSET
#undef COMPUTE

  const f32x16 oacc = oa0 + oa1;
  const float lsum = (ls0 + ls1) + (ls2 + ls3);
  const float tot = lsum + __shfl_xor(lsum, 32);
  if (hi == 0) inv_s[wave * 32 + ln] = __builtin_amdgcn_rcpf(tot);
  const int ROWS[16] = {0,1,2,3,8,9,10,11,16,17,18,19,24,25,26,27};
#pragma unroll
  for (int r = 0; r < 16; ++r) {
    const int row = ROWS[r] + 4 * hi;
    const float o = oacc[r] * inv_s[wave * 32 + row];
    const float hs = o * fminf(fmaxf(o + 3.f, 0.f), 6.f) * (1.f / 6.f);
    hsO[((size_t)(b * 1024 + q0 + row) << 10) + h * 32 + ln] = f2b(hs);
  }
}

// ---------------- output projection GEMM: [4096,1024] x [512,1024]^T, 64x64 tiles ----------------
__global__ __launch_bounds__(256) void gemm_proj(
    const uint16_t* __restrict__ Aop, const uint16_t* __restrict__ Bop,
    float* __restrict__ Cout, const float* __restrict__ bias) {
  const int K = 1024;
  __shared__ uint16_t As[2][64 * 32];
  __shared__ uint16_t Bs[2][64 * 32];
  const int tid = threadIdx.x;
  const int lane = tid & 63;
  const int wave = tid >> 6;
  const int am0 = blockIdx.y * 64;
  const int bn0 = blockIdx.x * 64;
  const int m_off = (wave >> 1) * 32;
  const int n_off = (wave & 1) * 32;
  const int sr = tid >> 2;
  const int sc = (tid & 3) << 3;

  auto stage = [&](int buf, int kt) {
    const int k0 = kt << 5;
    GLD16(Aop + (size_t)(am0 + sr) * K + (k0 + sc), &As[buf][tid * 8]);
    GLD16(Bop + (size_t)(bn0 + sr) * K + (k0 + sc), &Bs[buf][tid * 8]);
  };

  f32x4 acc[2][2] = {};
  stage(0, 0);
  asm volatile("s_waitcnt vmcnt(0)" ::: "memory");
  __syncthreads();

  const int fr = lane & 15;
  const int fk = (lane >> 4) << 3;
  int cur = 0;
  for (int kt = 0; kt < 32; ++kt) {
    if (kt + 1 < 32) stage(cur ^ 1, kt + 1);
    bf16x8 af[2], bf_[2];
#pragma unroll
    for (int mi = 0; mi < 2; ++mi)
      af[mi] = *(const bf16x8*)&As[cur][(m_off + mi * 16 + fr) * 32 + fk];
#pragma unroll
    for (int ni = 0; ni < 2; ++ni)
      bf_[ni] = *(const bf16x8*)&Bs[cur][(n_off + ni * 16 + fr) * 32 + fk];
#pragma unroll
    for (int mi = 0; mi < 2; ++mi)
#pragma unroll
      for (int ni = 0; ni < 2; ++ni)
        acc[mi][ni] = __builtin_amdgcn_mfma_f32_16x16x32_bf16(af[mi], bf_[ni], acc[mi][ni], 0, 0, 0);
    asm volatile("s_waitcnt vmcnt(0)" ::: "memory");
    __syncthreads();
    cur ^= 1;
  }

  const int rb = (lane >> 4) << 2;
  const int cl = lane & 15;
#pragma unroll
  for (int mi = 0; mi < 2; ++mi)
#pragma unroll
    for (int ni = 0; ni < 2; ++ni) {
      const int cg = bn0 + n_off + ni * 16 + cl;
#pragma unroll
      for (int r = 0; r < 4; ++r) {
        const int rg = am0 + m_off + mi * 16 + rb + r;
        Cout[(size_t)rg * 512 + cg] = acc[mi][ni][r] + bias[cg];
      }
    }
}

// ---------------- launch ----------------
extern "C" void kernel_launch(void* const* d_in, const int* in_sizes, int n_in,
                              void* d_out, int out_size, void* d_ws, size_t ws_size,
                              hipStream_t stream) {
  const float* x      = (const float*)d_in[0];
  const float* w_qkv  = (const float*)d_in[1];
  const float* dwk    = (const float*)d_in[2];
  const float* abias  = (const float*)d_in[3];
  const float* pw     = (const float*)d_in[4];
  const float* pb     = (const float*)d_in[5];
  float* out = (float*)d_out;

  char* ws = (char*)d_ws;
  uint16_t* xb   = (uint16_t*)(ws);                 // 4 MB
  uint16_t* wqb  = (uint16_t*)(ws + (4ull << 20));  // 2 MB
  uint16_t* pwb  = (uint16_t*)(ws + (6ull << 20));  // 1 MB
  uint16_t* qT   = (uint16_t*)(ws + (7ull << 20));  // 4 MB  (transposed, pre-scaled)
  uint16_t* kbuf = (uint16_t*)(ws + (11ull << 20)); // 4 MB
  uint16_t* vimg = (uint16_t*)(ws + (15ull << 20)); // 8 MB  (later reused as hsO)
  uint16_t* vcv  = (uint16_t*)(ws + (23ull << 20)); // 8 MB  (channel-major = V^T)
  uint16_t* bt2b = (uint16_t*)(ws + (31ull << 20)); // 4 MB  bf16 bias tiles, C-layout
  uint16_t* hsO  = vimg;                            // alias: vimg dead after dwconv

  prep<<<5600, 256, 0, stream>>>(x, w_qkv, pw, abias, xb, wqb, pwb, bt2b);
  gemm_qkv<<<dim3(16, 32), 256, 0, stream>>>(xb, wqb, qT, kbuf, vimg);
  dwconv3x3<<<4096, 256, 0, stream>>>(vimg, dwk, vcv);
  attn_mfma<<<1024, 256, 0, stream>>>(qT, kbuf, vcv, bt2b, hsO);
  gemm_proj<<<dim3(8, 64), 256, 0, stream>>>(hsO, pwb, out, pb);
}

// Round 8
// 100.912 us; speedup vs baseline: 1.0844x; 1.0844x over previous
//
#include <hip/hip_runtime.h>
#include <stdint.h>

#define HEADS 32
#define HW_N 1024
#define QS 0.36067376022224085f   // 0.25 * log2(e)
#define LOG2E 1.4426950408889634f

typedef __attribute__((ext_vector_type(8))) __bf16 bf16x8;
typedef __attribute__((ext_vector_type(4))) float f32x4;
typedef __attribute__((ext_vector_type(16))) float f32x16;
typedef __attribute__((ext_vector_type(4))) uint32_t u32x4;

__device__ __forceinline__ float b2f(uint16_t u) {
  union { uint32_t i; float f; } v; v.i = ((uint32_t)u) << 16; return v.f;
}
__device__ __forceinline__ uint16_t f2b(float f) {
  uint32_t u = __builtin_bit_cast(uint32_t, f);
  return (uint16_t)((u + 0x7FFFu + ((u >> 16) & 1u)) >> 16);
}

#define GLD16(g, s) __builtin_amdgcn_global_load_lds( \
    (const __attribute__((address_space(1))) void*)(g), \
    (__attribute__((address_space(3))) void*)(s), 16, 0, 0)

// ---------------- prep: f32->bf16 converts + bf16 bias tiles in MFMA C-layout ----------------
__global__ __launch_bounds__(256) void prep(const float* __restrict__ x,
                                            const float* __restrict__ wqv,
                                            const float* __restrict__ pw,
                                            const float* __restrict__ abias,
                                            uint16_t* __restrict__ xb,
                                            uint16_t* __restrict__ wqb,
                                            uint16_t* __restrict__ pwb,
                                            uint16_t* __restrict__ bt2b) {
  const int blk = blockIdx.x;
  const int tid = threadIdx.x;
  if (blk < 3584) {
    const float* in; uint16_t* out; int i;
    if (blk < 2048)      { in = x;   out = xb;  i = blk * 256 + tid; }
    else if (blk < 3072) { in = wqv; out = wqb; i = (blk - 2048) * 256 + tid; }
    else                 { in = pw;  out = pwb; i = (blk - 3072) * 256 + tid; }
    float4 v = ((const float4*)in)[i];
    ushort4 o;
    o.x = f2b(v.x); o.y = f2b(v.y); o.z = f2b(v.z); o.w = f2b(v.w);
    ((ushort4*)out)[i] = o;
  } else {
    const int blk2 = blk - 3584;           // 0..2015
    const int h = blk2 / 63, d31 = blk2 - h * 63;
    const size_t tb = ((size_t)(h * 63 + d31)) << 10;
#pragma unroll
    for (int c = 0; c < 4; ++c) {
      const int idx = c * 256 + tid;       // lane*16 + r
      const int lane = idx >> 4, r = idx & 15;
      const int hi = lane >> 5, ln = lane & 31;
      const int crow = (r & 3) + 8 * (r >> 2) + 4 * hi;
      const int col = 31 + ln - crow;      // 0..62
      bt2b[tb + idx] = f2b(LOG2E * abias[(size_t)(d31 * 63 + col) * 32 + h]);
    }
  }
}

// ---------------- QKV projection GEMM: [4096,512] x [2048,512]^T ----------------
__global__ __launch_bounds__(256) void gemm_qkv(
    const uint16_t* __restrict__ Aop, const uint16_t* __restrict__ Bop,
    uint16_t* __restrict__ qT, uint16_t* __restrict__ ko, uint16_t* __restrict__ vo) {
  const int K = 512;
  __shared__ uint16_t As[2][128 * 32];
  __shared__ uint16_t Bs[2][128 * 32];
  const int tid = threadIdx.x;
  const int lane = tid & 63;
  const int wave = tid >> 6;
  const int am0 = blockIdx.y * 128;
  const int bn0 = blockIdx.x * 128;
  const int m_off = (wave >> 1) * 64;
  const int n_off = (wave & 1) * 64;
  const int sr = tid >> 2;
  const int sc = (tid & 3) << 3;

  auto stage = [&](int buf, int kt) {
    const int k0 = kt << 5;
    GLD16(Aop + (size_t)(am0 + sr) * K + (k0 + sc), &As[buf][tid * 8]);
    GLD16(Aop + (size_t)(am0 + sr + 64) * K + (k0 + sc), &As[buf][(tid + 256) * 8]);
    GLD16(Bop + (size_t)(bn0 + sr) * K + (k0 + sc), &Bs[buf][tid * 8]);
    GLD16(Bop + (size_t)(bn0 + sr + 64) * K + (k0 + sc), &Bs[buf][(tid + 256) * 8]);
  };

  f32x4 acc[4][4] = {};
  stage(0, 0);
  asm volatile("s_waitcnt vmcnt(0)" ::: "memory");
  __syncthreads();

  const int fr = lane & 15;
  const int fk = (lane >> 4) << 3;
  int cur = 0;
  for (int kt = 0; kt < 16; ++kt) {
    if (kt + 1 < 16) stage(cur ^ 1, kt + 1);
    bf16x8 af[4], bf_[4];
#pragma unroll
    for (int mi = 0; mi < 4; ++mi)
      af[mi] = *(const bf16x8*)&As[cur][(m_off + mi * 16 + fr) * 32 + fk];
#pragma unroll
    for (int ni = 0; ni < 4; ++ni)
      bf_[ni] = *(const bf16x8*)&Bs[cur][(n_off + ni * 16 + fr) * 32 + fk];
#pragma unroll
    for (int mi = 0; mi < 4; ++mi)
#pragma unroll
      for (int ni = 0; ni < 4; ++ni)
        acc[mi][ni] = __builtin_amdgcn_mfma_f32_16x16x32_bf16(af[mi], bf_[ni], acc[mi][ni], 0, 0, 0);
    asm volatile("s_waitcnt vmcnt(0)" ::: "memory");
    __syncthreads();
    cur ^= 1;
  }

  const int rb = (lane >> 4) << 2;
  const int cl = lane & 15;
  const int b = am0 >> 10;
  const int h = (bn0 + n_off) >> 6;
  const int bh = b * 32 + h;
#pragma unroll
  for (int mi = 0; mi < 4; ++mi) {
    const int n0 = (am0 & 1023) + m_off + mi * 16 + rb;
    {  // q: transposed + pre-scaled, packed along rows
      ushort4 o;
      o.x = f2b(acc[mi][0][0] * QS); o.y = f2b(acc[mi][0][1] * QS);
      o.z = f2b(acc[mi][0][2] * QS); o.w = f2b(acc[mi][0][3] * QS);
      *(ushort4*)&qT[((size_t)(bh * 16 + cl) << 10) + n0] = o;
    }
#pragma unroll
    for (int r = 0; r < 4; ++r)  // k: row-major
      ko[((size_t)(bh * 1024 + n0 + r)) * 16 + cl] = f2b(acc[mi][1][r]);
#pragma unroll
    for (int nv = 2; nv < 4; ++nv) {  // v: channel-major (V^T), packed
      const int l = h * 32 + (nv - 2) * 16 + cl;
      ushort4 o;
      o.x = f2b(acc[mi][nv][0]); o.y = f2b(acc[mi][nv][1]);
      o.z = f2b(acc[mi][nv][2]); o.w = f2b(acc[mi][nv][3]);
      *(ushort4*)&vo[((size_t)(b * 1024 + l) << 10) + n0] = o;
    }
  }
}

// ---------------- depthwise 3x3 conv (SAME), channel-major in AND out ----------------
__global__ __launch_bounds__(256) void dwconv3x3(const uint16_t* __restrict__ vimg,
                                                 const float* __restrict__ kw,
                                                 uint16_t* __restrict__ vcv) {
  __shared__ float t[1024];
  const int bl = blockIdx.x;  // b*1024 + l
  const int l = bl & 1023;
  const int tid = threadIdx.x;
  const uint16_t* src = vimg + (size_t)bl * 1024;
  {
    uint2 vv = ((const uint2*)src)[tid];
    t[tid * 4 + 0] = b2f((uint16_t)vv.x);
    t[tid * 4 + 1] = b2f((uint16_t)(vv.x >> 16));
    t[tid * 4 + 2] = b2f((uint16_t)vv.y);
    t[tid * 4 + 3] = b2f((uint16_t)(vv.y >> 16));
  }
  float w[9];
#pragma unroll
  for (int i = 0; i < 9; ++i) w[i] = kw[l * 9 + i];
  __syncthreads();
  uint16_t* dst = vcv + (size_t)bl * 1024;
#pragma unroll
  for (int i = 0; i < 4; ++i) {
    const int p = tid + i * 256;
    const int y = p >> 5, x = p & 31;
    float a = 0.f;
#pragma unroll
    for (int dy = 0; dy < 3; ++dy) {
      const int yy = y + dy - 1;
      if (yy < 0 || yy > 31) continue;
#pragma unroll
      for (int dx = 0; dx < 3; ++dx) {
        const int xx = x + dx - 1;
        if (xx < 0 || xx > 31) continue;
        a += t[yy * 32 + xx] * w[dy * 3 + dx];
      }
    }
    dst[p] = f2b(a);
  }
}

// ---------------- MFMA fused attention + hardswish ----------------
// 1-wave blocks (grid 4096). Swapped QK^T, bf16 bias tiles as MFMA C-operand,
// v_perm pack + permlane32_swap exchange (verified r7). Prefetch: K & bias at
// distance 2 (4 static slots), V at distance 1 (2 slots), unroll-4 body.
__global__ __launch_bounds__(64, 3) void attn_mfma(
    const uint16_t* __restrict__ qT, const uint16_t* __restrict__ kb,
    const uint16_t* __restrict__ vt, const uint16_t* __restrict__ bt2b,
    uint16_t* __restrict__ hsO) {
  __shared__ float inv_s[32];
  const int blk = blockIdx.x;
  const int bh = blk & 127;   // qt in high bits: 32 sibling blocks share (b,h) & XCD
  const int qt = blk >> 7;    // 0..31
  const int b = bh >> 5, h = bh & 31;
  const int lane = threadIdx.x;
  const int hi = lane >> 5, ln = lane & 31;

  const int q0 = qt * 32;
  const int qi = qt;

  union { ushort u[8]; bf16x8 v; } qu;
#pragma unroll
  for (int j = 0; j < 8; ++j)
    qu.u[j] = qT[((size_t)(bh * 16 + hi * 8 + j) << 10) + q0 + ln];
  const bf16x8 qf = qu.v;

  const uint16_t* kp = kb + ((size_t)bh * 1024 + ln) * 16 + hi * 8;
  const uint16_t* vp = vt + ((size_t)(b * 1024 + h * 32 + ln) << 10) + hi * 8;
  const uint16_t* bp = bt2b + ((size_t)(h * 63 + qi + 31) << 10) + lane * 16;

  f32x16 oa0 = {}, oa1 = {};
  float ls0 = 0.f, ls1 = 0.f, ls2 = 0.f, ls3 = 0.f;

#define LK(kf, off) kf = *(const bf16x8*)(kp + (off) * 512)
#define LV(v0, v1, off) do {                                          \
    v0 = *(const bf16x8*)(vp + (off) * 32);                           \
    v1 = *(const bf16x8*)(vp + (off) * 32 + 16);                      \
  } while (0)
#define LB(ca, cb, off) do {                                          \
    ca = *(const u32x4*)(bp - (off) * 1024);                          \
    cb = *(const u32x4*)(bp - (off) * 1024 + 8);                      \
  } while (0)

#define COMPUTE(kf, ca, cb, vf0, vf1, oacc, lsA, lsB) do {            \
    f32x16 cc;                                                        \
    _Pragma("unroll")                                                 \
    for (int j = 0; j < 4; ++j) {                                     \
      const uint32_t ua = ca[j], ub = cb[j];                          \
      cc[2 * j]     = __builtin_bit_cast(float, ua << 16);            \
      cc[2 * j + 1] = __builtin_bit_cast(float, ua & 0xFFFF0000u);    \
      cc[8 + 2 * j]     = __builtin_bit_cast(float, ub << 16);        \
      cc[8 + 2 * j + 1] = __builtin_bit_cast(float, ub & 0xFFFF0000u);\
    }                                                                 \
    const f32x16 s = __builtin_amdgcn_mfma_f32_32x32x16_bf16(kf, qf, cc, 0, 0, 0); \
    float p[16];                                                      \
    _Pragma("unroll")                                                 \
    for (int r = 0; r < 16; ++r) p[r] = __builtin_amdgcn_exp2f(s[r]); \
    _Pragma("unroll")                                                 \
    for (int r = 0; r < 8; ++r) { lsA += p[r]; lsB += p[r + 8]; }     \
    uint32_t w0, w1, w2, w3, w4, w5, w6, w7;                          \
    w0 = __builtin_amdgcn_perm(__builtin_bit_cast(uint32_t, p[1]),  __builtin_bit_cast(uint32_t, p[0]),  0x07060302u); \
    w1 = __builtin_amdgcn_perm(__builtin_bit_cast(uint32_t, p[3]),  __builtin_bit_cast(uint32_t, p[2]),  0x07060302u); \
    w2 = __builtin_amdgcn_perm(__builtin_bit_cast(uint32_t, p[5]),  __builtin_bit_cast(uint32_t, p[4]),  0x07060302u); \
    w3 = __builtin_amdgcn_perm(__builtin_bit_cast(uint32_t, p[7]),  __builtin_bit_cast(uint32_t, p[6]),  0x07060302u); \
    w4 = __builtin_amdgcn_perm(__builtin_bit_cast(uint32_t, p[9]),  __builtin_bit_cast(uint32_t, p[8]),  0x07060302u); \
    w5 = __builtin_amdgcn_perm(__builtin_bit_cast(uint32_t, p[11]), __builtin_bit_cast(uint32_t, p[10]), 0x07060302u); \
    w6 = __builtin_amdgcn_perm(__builtin_bit_cast(uint32_t, p[13]), __builtin_bit_cast(uint32_t, p[12]), 0x07060302u); \
    w7 = __builtin_amdgcn_perm(__builtin_bit_cast(uint32_t, p[15]), __builtin_bit_cast(uint32_t, p[14]), 0x07060302u); \
    asm("v_permlane32_swap_b32 %0, %1" : "+v"(w0), "+v"(w2));         \
    asm("v_permlane32_swap_b32 %0, %1" : "+v"(w1), "+v"(w3));         \
    asm("v_permlane32_swap_b32 %0, %1" : "+v"(w4), "+v"(w6));         \
    asm("v_permlane32_swap_b32 %0, %1" : "+v"(w5), "+v"(w7));         \
    const u32x4 a0u = {w0, w1, w2, w3};                               \
    const u32x4 a1u = {w4, w5, w6, w7};                               \
    oacc = __builtin_amdgcn_mfma_f32_32x32x16_bf16(                   \
        __builtin_bit_cast(bf16x8, a0u), vf0, oacc, 0, 0, 0);         \
    oacc = __builtin_amdgcn_mfma_f32_32x32x16_bf16(                   \
        __builtin_bit_cast(bf16x8, a1u), vf1, oacc, 0, 0, 0);         \
  } while (0)

  bf16x8 k0, k1, k2, k3, v0a, v0b, v1a, v1b;
  u32x4 c0a, c0b, c1a, c1b, c2a, c2b, c3a, c3b;
  LK(k0, 0); LB(c0a, c0b, 0);
  LK(k1, 1); LB(c1a, c1b, 1);
  LV(v0a, v0b, 0);
  for (int t = 0; t < 32; t += 4) {
    LK(k2, 2); LB(c2a, c2b, 2); LV(v1a, v1b, 1);
    COMPUTE(k0, c0a, c0b, v0a, v0b, oa0, ls0, ls1);   // tile t
    LK(k3, 3); LB(c3a, c3b, 3); LV(v0a, v0b, 2);
    COMPUTE(k1, c1a, c1b, v1a, v1b, oa1, ls2, ls3);   // tile t+1
    LK(k0, 4); LB(c0a, c0b, 4); LV(v1a, v1b, 3);
    COMPUTE(k2, c2a, c2b, v0a, v0b, oa0, ls0, ls1);   // tile t+2
    LK(k1, 5); LB(c1a, c1b, 5); LV(v0a, v0b, 4);
    COMPUTE(k3, c3a, c3b, v1a, v1b, oa1, ls2, ls3);   // tile t+3
    kp += 4 * 512; vp += 4 * 32; bp -= 4 * 1024;      // advance 4 tiles
  }
#undef LK
#undef LV
#undef LB
#undef COMPUTE

  const f32x16 oacc = oa0 + oa1;
  const float lsum = (ls0 + ls1) + (ls2 + ls3);
  const float tot = lsum + __shfl_xor(lsum, 32);
  if (hi == 0) inv_s[ln] = __builtin_amdgcn_rcpf(tot);
  const int ROWS[16] = {0,1,2,3,8,9,10,11,16,17,18,19,24,25,26,27};
#pragma unroll
  for (int r = 0; r < 16; ++r) {
    const int row = ROWS[r] + 4 * hi;
    const float o = oacc[r] * inv_s[row];
    const float hs = o * fminf(fmaxf(o + 3.f, 0.f), 6.f) * (1.f / 6.f);
    hsO[((size_t)(b * 1024 + q0 + row) << 10) + h * 32 + ln] = f2b(hs);
  }
}

// ---------------- output projection GEMM: [4096,1024] x [512,1024]^T, 64x64 tiles ----------------
__global__ __launch_bounds__(256) void gemm_proj(
    const uint16_t* __restrict__ Aop, const uint16_t* __restrict__ Bop,
    float* __restrict__ Cout, const float* __restrict__ bias) {
  const int K = 1024;
  __shared__ uint16_t As[2][64 * 32];
  __shared__ uint16_t Bs[2][64 * 32];
  const int tid = threadIdx.x;
  const int lane = tid & 63;
  const int wave = tid >> 6;
  const int am0 = blockIdx.y * 64;
  const int bn0 = blockIdx.x * 64;
  const int m_off = (wave >> 1) * 32;
  const int n_off = (wave & 1) * 32;
  const int sr = tid >> 2;
  const int sc = (tid & 3) << 3;

  auto stage = [&](int buf, int kt) {
    const int k0 = kt << 5;
    GLD16(Aop + (size_t)(am0 + sr) * K + (k0 + sc), &As[buf][tid * 8]);
    GLD16(Bop + (size_t)(bn0 + sr) * K + (k0 + sc), &Bs[buf][tid * 8]);
  };

  f32x4 acc[2][2] = {};
  stage(0, 0);
  asm volatile("s_waitcnt vmcnt(0)" ::: "memory");
  __syncthreads();

  const int fr = lane & 15;
  const int fk = (lane >> 4) << 3;
  int cur = 0;
  for (int kt = 0; kt < 32; ++kt) {
    if (kt + 1 < 32) stage(cur ^ 1, kt + 1);
    bf16x8 af[2], bf_[2];
#pragma unroll
    for (int mi = 0; mi < 2; ++mi)
      af[mi] = *(const bf16x8*)&As[cur][(m_off + mi * 16 + fr) * 32 + fk];
#pragma unroll
    for (int ni = 0; ni < 2; ++ni)
      bf_[ni] = *(const bf16x8*)&Bs[cur][(n_off + ni * 16 + fr) * 32 + fk];
#pragma unroll
    for (int mi = 0; mi < 2; ++mi)
#pragma unroll
      for (int ni = 0; ni < 2; ++ni)
        acc[mi][ni] = __builtin_amdgcn_mfma_f32_16x16x32_bf16(af[mi], bf_[ni], acc[mi][ni], 0, 0, 0);
    asm volatile("s_waitcnt vmcnt(0)" ::: "memory");
    __syncthreads();
    cur ^= 1;
  }

  const int rb = (lane >> 4) << 2;
  const int cl = lane & 15;
#pragma unroll
  for (int mi = 0; mi < 2; ++mi)
#pragma unroll
    for (int ni = 0; ni < 2; ++ni) {
      const int cg = bn0 + n_off + ni * 16 + cl;
#pragma unroll
      for (int r = 0; r < 4; ++r) {
        const int rg = am0 + m_off + mi * 16 + rb + r;
        Cout[(size_t)rg * 512 + cg] = acc[mi][ni][r] + bias[cg];
      }
    }
}

// ---------------- launch ----------------
extern "C" void kernel_launch(void* const* d_in, const int* in_sizes, int n_in,
                              void* d_out, int out_size, void* d_ws, size_t ws_size,
                              hipStream_t stream) {
  const float* x      = (const float*)d_in[0];
  const float* w_qkv  = (const float*)d_in[1];
  const float* dwk    = (const float*)d_in[2];
  const float* abias  = (const float*)d_in[3];
  const float* pw     = (const float*)d_in[4];
  const float* pb     = (const float*)d_in[5];
  float* out = (float*)d_out;

  char* ws = (char*)d_ws;
  uint16_t* xb   = (uint16_t*)(ws);                 // 4 MB
  uint16_t* wqb  = (uint16_t*)(ws + (4ull << 20));  // 2 MB
  uint16_t* pwb  = (uint16_t*)(ws + (6ull << 20));  // 1 MB
  uint16_t* qT   = (uint16_t*)(ws + (7ull << 20));  // 4 MB  (transposed, pre-scaled)
  uint16_t* kbuf = (uint16_t*)(ws + (11ull << 20)); // 4 MB
  uint16_t* vimg = (uint16_t*)(ws + (15ull << 20)); // 8 MB  (later reused as hsO)
  uint16_t* vcv  = (uint16_t*)(ws + (23ull << 20)); // 8 MB  (channel-major = V^T)
  uint16_t* bt2b = (uint16_t*)(ws + (31ull << 20)); // 4 MB  bf16 bias tiles, C-layout
  uint16_t* hsO  = vimg;                            // alias: vimg dead after dwconv

  prep<<<5600, 256, 0, stream>>>(x, w_qkv, pw, abias, xb, wqb, pwb, bt2b);
  gemm_qkv<<<dim3(16, 32), 256, 0, stream>>>(xb, wqb, qT, kbuf, vimg);
  dwconv3x3<<<4096, 256, 0, stream>>>(vimg, dwk, vcv);
  attn_mfma<<<4096, 64, 0, stream>>>(qT, kbuf, vcv, bt2b, hsO);
  gemm_proj<<<dim3(8, 64), 256, 0, stream>>>(hsO, pwb, out, pb);
}

// Round 10
// 100.010 us; speedup vs baseline: 1.0942x; 1.0090x over previous
//
#include <hip/hip_runtime.h>
#include <stdint.h>

#define HEADS 32
#define HW_N 1024
#define QS 0.36067376022224085f   // 0.25 * log2(e)
#define LOG2E 1.4426950408889634f

typedef __attribute__((ext_vector_type(8))) __bf16 bf16x8;
typedef __attribute__((ext_vector_type(4))) float f32x4;
typedef __attribute__((ext_vector_type(16))) float f32x16;
typedef __attribute__((ext_vector_type(4))) uint32_t u32x4;

__device__ __forceinline__ float b2f(uint16_t u) {
  union { uint32_t i; float f; } v; v.i = ((uint32_t)u) << 16; return v.f;
}
__device__ __forceinline__ uint16_t f2b(float f) {
  uint32_t u = __builtin_bit_cast(uint32_t, f);
  return (uint16_t)((u + 0x7FFFu + ((u >> 16) & 1u)) >> 16);
}

#define GLD16(g, s) __builtin_amdgcn_global_load_lds( \
    (const __attribute__((address_space(1))) void*)(g), \
    (__attribute__((address_space(3))) void*)(s), 16, 0, 0)

// ---------------- prep: f32->bf16 converts + bf16 bias tiles in MFMA C-layout ----------------
__global__ __launch_bounds__(256) void prep(const float* __restrict__ x,
                                            const float* __restrict__ wqv,
                                            const float* __restrict__ pw,
                                            const float* __restrict__ abias,
                                            uint16_t* __restrict__ xb,
                                            uint16_t* __restrict__ wqb,
                                            uint16_t* __restrict__ pwb,
                                            uint16_t* __restrict__ bt2b) {
  const int blk = blockIdx.x;
  const int tid = threadIdx.x;
  if (blk < 3584) {
    const float* in; uint16_t* out; int i;
    if (blk < 2048)      { in = x;   out = xb;  i = blk * 256 + tid; }
    else if (blk < 3072) { in = wqv; out = wqb; i = (blk - 2048) * 256 + tid; }
    else                 { in = pw;  out = pwb; i = (blk - 3072) * 256 + tid; }
    float4 v = ((const float4*)in)[i];
    ushort4 o;
    o.x = f2b(v.x); o.y = f2b(v.y); o.z = f2b(v.z); o.w = f2b(v.w);
    ((ushort4*)out)[i] = o;
  } else {
    const int blk2 = blk - 3584;           // 0..2015
    const int h = blk2 / 63, d31 = blk2 - h * 63;
    const size_t tb = ((size_t)(h * 63 + d31)) << 10;
#pragma unroll
    for (int c = 0; c < 4; ++c) {
      const int idx = c * 256 + tid;       // lane*16 + r
      const int lane = idx >> 4, r = idx & 15;
      const int hi = lane >> 5, ln = lane & 31;
      const int crow = (r & 3) + 8 * (r >> 2) + 4 * hi;
      const int col = 31 + ln - crow;      // 0..62
      bt2b[tb + idx] = f2b(LOG2E * abias[(size_t)(d31 * 63 + col) * 32 + h]);
    }
  }
}

// ---------------- QKV projection GEMM: [4096,512] x [2048,512]^T ----------------
__global__ __launch_bounds__(256) void gemm_qkv(
    const uint16_t* __restrict__ Aop, const uint16_t* __restrict__ Bop,
    uint16_t* __restrict__ qT, uint16_t* __restrict__ ko, uint16_t* __restrict__ vo) {
  const int K = 512;
  __shared__ uint16_t As[2][128 * 32];
  __shared__ uint16_t Bs[2][128 * 32];
  const int tid = threadIdx.x;
  const int lane = tid & 63;
  const int wave = tid >> 6;
  const int am0 = blockIdx.y * 128;
  const int bn0 = blockIdx.x * 128;
  const int m_off = (wave >> 1) * 64;
  const int n_off = (wave & 1) * 64;
  const int sr = tid >> 2;
  const int sc = (tid & 3) << 3;

  auto stage = [&](int buf, int kt) {
    const int k0 = kt << 5;
    GLD16(Aop + (size_t)(am0 + sr) * K + (k0 + sc), &As[buf][tid * 8]);
    GLD16(Aop + (size_t)(am0 + sr + 64) * K + (k0 + sc), &As[buf][(tid + 256) * 8]);
    GLD16(Bop + (size_t)(bn0 + sr) * K + (k0 + sc), &Bs[buf][tid * 8]);
    GLD16(Bop + (size_t)(bn0 + sr + 64) * K + (k0 + sc), &Bs[buf][(tid + 256) * 8]);
  };

  f32x4 acc[4][4] = {};
  stage(0, 0);
  asm volatile("s_waitcnt vmcnt(0)" ::: "memory");
  __syncthreads();

  const int fr = lane & 15;
  const int fk = (lane >> 4) << 3;
  int cur = 0;
  for (int kt = 0; kt < 16; ++kt) {
    if (kt + 1 < 16) stage(cur ^ 1, kt + 1);
    bf16x8 af[4], bf_[4];
#pragma unroll
    for (int mi = 0; mi < 4; ++mi)
      af[mi] = *(const bf16x8*)&As[cur][(m_off + mi * 16 + fr) * 32 + fk];
#pragma unroll
    for (int ni = 0; ni < 4; ++ni)
      bf_[ni] = *(const bf16x8*)&Bs[cur][(n_off + ni * 16 + fr) * 32 + fk];
#pragma unroll
    for (int mi = 0; mi < 4; ++mi)
#pragma unroll
      for (int ni = 0; ni < 4; ++ni)
        acc[mi][ni] = __builtin_amdgcn_mfma_f32_16x16x32_bf16(af[mi], bf_[ni], acc[mi][ni], 0, 0, 0);
    asm volatile("s_waitcnt vmcnt(0)" ::: "memory");
    __syncthreads();
    cur ^= 1;
  }

  const int rb = (lane >> 4) << 2;
  const int cl = lane & 15;
  const int b = am0 >> 10;
  const int h = (bn0 + n_off) >> 6;
  const int bh = b * 32 + h;
#pragma unroll
  for (int mi = 0; mi < 4; ++mi) {
    const int n0 = (am0 & 1023) + m_off + mi * 16 + rb;
    {  // q: transposed + pre-scaled, packed along rows
      ushort4 o;
      o.x = f2b(acc[mi][0][0] * QS); o.y = f2b(acc[mi][0][1] * QS);
      o.z = f2b(acc[mi][0][2] * QS); o.w = f2b(acc[mi][0][3] * QS);
      *(ushort4*)&qT[((size_t)(bh * 16 + cl) << 10) + n0] = o;
    }
#pragma unroll
    for (int r = 0; r < 4; ++r)  // k: row-major
      ko[((size_t)(bh * 1024 + n0 + r)) * 16 + cl] = f2b(acc[mi][1][r]);
#pragma unroll
    for (int nv = 2; nv < 4; ++nv) {  // v: channel-major (V^T), packed
      const int l = h * 32 + (nv - 2) * 16 + cl;
      ushort4 o;
      o.x = f2b(acc[mi][nv][0]); o.y = f2b(acc[mi][nv][1]);
      o.z = f2b(acc[mi][nv][2]); o.w = f2b(acc[mi][nv][3]);
      *(ushort4*)&vo[((size_t)(b * 1024 + l) << 10) + n0] = o;
    }
  }
}

// ---------------- depthwise 3x3 conv (SAME), channel-major in AND out ----------------
__global__ __launch_bounds__(256) void dwconv3x3(const uint16_t* __restrict__ vimg,
                                                 const float* __restrict__ kw,
                                                 uint16_t* __restrict__ vcv) {
  __shared__ float t[1024];
  const int bl = blockIdx.x;  // b*1024 + l
  const int l = bl & 1023;
  const int tid = threadIdx.x;
  const uint16_t* src = vimg + (size_t)bl * 1024;
  {
    uint2 vv = ((const uint2*)src)[tid];
    t[tid * 4 + 0] = b2f((uint16_t)vv.x);
    t[tid * 4 + 1] = b2f((uint16_t)(vv.x >> 16));
    t[tid * 4 + 2] = b2f((uint16_t)vv.y);
    t[tid * 4 + 3] = b2f((uint16_t)(vv.y >> 16));
  }
  float w[9];
#pragma unroll
  for (int i = 0; i < 9; ++i) w[i] = kw[l * 9 + i];
  __syncthreads();
  uint16_t* dst = vcv + (size_t)bl * 1024;
#pragma unroll
  for (int i = 0; i < 4; ++i) {
    const int p = tid + i * 256;
    const int y = p >> 5, x = p & 31;
    float a = 0.f;
#pragma unroll
    for (int dy = 0; dy < 3; ++dy) {
      const int yy = y + dy - 1;
      if (yy < 0 || yy > 31) continue;
#pragma unroll
      for (int dx = 0; dx < 3; ++dx) {
        const int xx = x + dx - 1;
        if (xx < 0 || xx > 31) continue;
        a += t[yy * 32 + xx] * w[dy * 3 + dx];
      }
    }
    dst[p] = f2b(a);
  }
}

// ---------------- MFMA fused attention + hardswish ----------------
// 1-wave blocks. Ping-pong depth-1 prefetch with NORMAL loads (compiler
// emits counted vmcnt) pinned by sched_barrier(0) region splits so the
// pre-RA scheduler cannot sink loads into the consuming region (r8 showed
// it collapses the pipeline: VGPR=64). Math identical to r7/r8 verified:
// swapped QK^T + bf16 bias C-operand + v_perm pack + permlane32_swap(w0,w2).
__global__ __launch_bounds__(64, 3) void attn_mfma(
    const uint16_t* __restrict__ qT, const uint16_t* __restrict__ kb,
    const uint16_t* __restrict__ vt, const uint16_t* __restrict__ bt2b,
    uint16_t* __restrict__ hsO) {
  __shared__ float inv_s[32];
  const int blk = blockIdx.x;
  const int bh = blk & 127;   // qt in high bits: 32 sibling blocks share (b,h) & XCD
  const int qt = blk >> 7;    // 0..31
  const int b = bh >> 5, h = bh & 31;
  const int lane = threadIdx.x;
  const int hi = lane >> 5, ln = lane & 31;

  const int q0 = qt * 32;
  const int qi = qt;

  union { ushort u[8]; bf16x8 v; } qu;
#pragma unroll
  for (int j = 0; j < 8; ++j)
    qu.u[j] = qT[((size_t)(bh * 16 + hi * 8 + j) << 10) + q0 + ln];
  const bf16x8 qf = qu.v;

  const uint16_t* kp = kb + ((size_t)bh * 1024 + ln) * 16 + hi * 8;
  const uint16_t* vp = vt + ((size_t)(b * 1024 + h * 32 + ln) << 10) + hi * 8;
  const uint16_t* bp = bt2b + ((size_t)(h * 63 + qi + 31) << 10) + lane * 16;

  f32x16 oacc = {};
  float ls0 = 0.f, ls1 = 0.f, ls2 = 0.f, ls3 = 0.f;

#define LOADSET(off, kf, v0, v1, ca, cb) do {                         \
    kf = *(const bf16x8*)(kp + (off) * 512);                          \
    v0 = *(const bf16x8*)(vp + (off) * 32);                           \
    v1 = *(const bf16x8*)(vp + (off) * 32 + 16);                      \
    ca = *(const u32x4*)(bp - (off) * 1024);                          \
    cb = *(const u32x4*)(bp - (off) * 1024 + 8);                      \
  } while (0)

#define COMPUTE(kf, ca, cb, vf0, vf1, lsA, lsB) do {                  \
    f32x16 cc;                                                        \
    _Pragma("unroll")                                                 \
    for (int j = 0; j < 4; ++j) {                                     \
      const uint32_t ua = ca[j], ub = cb[j];                          \
      cc[2 * j]     = __builtin_bit_cast(float, ua << 16);            \
      cc[2 * j + 1] = __builtin_bit_cast(float, ua & 0xFFFF0000u);    \
      cc[8 + 2 * j]     = __builtin_bit_cast(float, ub << 16);        \
      cc[8 + 2 * j + 1] = __builtin_bit_cast(float, ub & 0xFFFF0000u);\
    }                                                                 \
    const f32x16 s = __builtin_amdgcn_mfma_f32_32x32x16_bf16(kf, qf, cc, 0, 0, 0); \
    float p[16];                                                      \
    _Pragma("unroll")                                                 \
    for (int r = 0; r < 16; ++r) p[r] = __builtin_amdgcn_exp2f(s[r]); \
    _Pragma("unroll")                                                 \
    for (int r = 0; r < 8; ++r) { lsA += p[r]; lsB += p[r + 8]; }     \
    uint32_t w0, w1, w2, w3, w4, w5, w6, w7;                          \
    w0 = __builtin_amdgcn_perm(__builtin_bit_cast(uint32_t, p[1]),  __builtin_bit_cast(uint32_t, p[0]),  0x07060302u); \
    w1 = __builtin_amdgcn_perm(__builtin_bit_cast(uint32_t, p[3]),  __builtin_bit_cast(uint32_t, p[2]),  0x07060302u); \
    w2 = __builtin_amdgcn_perm(__builtin_bit_cast(uint32_t, p[5]),  __builtin_bit_cast(uint32_t, p[4]),  0x07060302u); \
    w3 = __builtin_amdgcn_perm(__builtin_bit_cast(uint32_t, p[7]),  __builtin_bit_cast(uint32_t, p[6]),  0x07060302u); \
    w4 = __builtin_amdgcn_perm(__builtin_bit_cast(uint32_t, p[9]),  __builtin_bit_cast(uint32_t, p[8]),  0x07060302u); \
    w5 = __builtin_amdgcn_perm(__builtin_bit_cast(uint32_t, p[11]), __builtin_bit_cast(uint32_t, p[10]), 0x07060302u); \
    w6 = __builtin_amdgcn_perm(__builtin_bit_cast(uint32_t, p[13]), __builtin_bit_cast(uint32_t, p[12]), 0x07060302u); \
    w7 = __builtin_amdgcn_perm(__builtin_bit_cast(uint32_t, p[15]), __builtin_bit_cast(uint32_t, p[14]), 0x07060302u); \
    asm("v_permlane32_swap_b32 %0, %1" : "+v"(w0), "+v"(w2));         \
    asm("v_permlane32_swap_b32 %0, %1" : "+v"(w1), "+v"(w3));         \
    asm("v_permlane32_swap_b32 %0, %1" : "+v"(w4), "+v"(w6));         \
    asm("v_permlane32_swap_b32 %0, %1" : "+v"(w5), "+v"(w7));         \
    const u32x4 a0u = {w0, w1, w2, w3};                               \
    const u32x4 a1u = {w4, w5, w6, w7};                               \
    oacc = __builtin_amdgcn_mfma_f32_32x32x16_bf16(                   \
        __builtin_bit_cast(bf16x8, a0u), vf0, oacc, 0, 0, 0);         \
    oacc = __builtin_amdgcn_mfma_f32_32x32x16_bf16(                   \
        __builtin_bit_cast(bf16x8, a1u), vf1, oacc, 0, 0, 0);         \
  } while (0)

#define FENCE __builtin_amdgcn_sched_barrier(0)

  bf16x8 kA, vA0, vA1, kB, vB0, vB1;
  u32x4 cA0, cA1, cB0, cB1;
  LOADSET(0, kA, vA0, vA1, cA0, cA1);          // tile 0
  FENCE;
  for (int t = 0; t < 32; t += 2) {
    LOADSET(1, kB, vB0, vB1, cB0, cB1);        // tile t+1
    FENCE;
    COMPUTE(kA, cA0, cA1, vA0, vA1, ls0, ls1); // tile t
    FENCE;
    kp += 1024; vp += 64; bp -= 2048;          // advance 2 tiles
    LOADSET(0, kA, vA0, vA1, cA0, cA1);        // tile t+2 (last iter: harmless ws read)
    FENCE;
    COMPUTE(kB, cB0, cB1, vB0, vB1, ls2, ls3); // tile t+1
    FENCE;
  }
#undef LOADSET
#undef COMPUTE
#undef FENCE

  const float lsum = (ls0 + ls1) + (ls2 + ls3);
  const float tot = lsum + __shfl_xor(lsum, 32);
  if (hi == 0) inv_s[ln] = __builtin_amdgcn_rcpf(tot);
  const int ROWS[16] = {0,1,2,3,8,9,10,11,16,17,18,19,24,25,26,27};
#pragma unroll
  for (int r = 0; r < 16; ++r) {
    const int row = ROWS[r] + 4 * hi;
    const float o = oacc[r] * inv_s[row];
    const float hs = o * fminf(fmaxf(o + 3.f, 0.f), 6.f) * (1.f / 6.f);
    hsO[((size_t)(b * 1024 + q0 + row) << 10) + h * 32 + ln] = f2b(hs);
  }
}

// ---------------- output projection GEMM: [4096,1024] x [512,1024]^T, 64x64 tiles ----------------
__global__ __launch_bounds__(256) void gemm_proj(
    const uint16_t* __restrict__ Aop, const uint16_t* __restrict__ Bop,
    float* __restrict__ Cout, const float* __restrict__ bias) {
  const int K = 1024;
  __shared__ uint16_t As[2][64 * 32];
  __shared__ uint16_t Bs[2][64 * 32];
  const int tid = threadIdx.x;
  const int lane = tid & 63;
  const int wave = tid >> 6;
  const int am0 = blockIdx.y * 64;
  const int bn0 = blockIdx.x * 64;
  const int m_off = (wave >> 1) * 32;
  const int n_off = (wave & 1) * 32;
  const int sr = tid >> 2;
  const int sc = (tid & 3) << 3;

  auto stage = [&](int buf, int kt) {
    const int k0 = kt << 5;
    GLD16(Aop + (size_t)(am0 + sr) * K + (k0 + sc), &As[buf][tid * 8]);
    GLD16(Bop + (size_t)(bn0 + sr) * K + (k0 + sc), &Bs[buf][tid * 8]);
  };

  f32x4 acc[2][2] = {};
  stage(0, 0);
  asm volatile("s_waitcnt vmcnt(0)" ::: "memory");
  __syncthreads();

  const int fr = lane & 15;
  const int fk = (lane >> 4) << 3;
  int cur = 0;
  for (int kt = 0; kt < 32; ++kt) {
    if (kt + 1 < 32) stage(cur ^ 1, kt + 1);
    bf16x8 af[2], bf_[2];
#pragma unroll
    for (int mi = 0; mi < 2; ++mi)
      af[mi] = *(const bf16x8*)&As[cur][(m_off + mi * 16 + fr) * 32 + fk];
#pragma unroll
    for (int ni = 0; ni < 2; ++ni)
      bf_[ni] = *(const bf16x8*)&Bs[cur][(n_off + ni * 16 + fr) * 32 + fk];
#pragma unroll
    for (int mi = 0; mi < 2; ++mi)
#pragma unroll
      for (int ni = 0; ni < 2; ++ni)
        acc[mi][ni] = __builtin_amdgcn_mfma_f32_16x16x32_bf16(af[mi], bf_[ni], acc[mi][ni], 0, 0, 0);
    asm volatile("s_waitcnt vmcnt(0)" ::: "memory");
    __syncthreads();
    cur ^= 1;
  }

  const int rb = (lane >> 4) << 2;
  const int cl = lane & 15;
#pragma unroll
  for (int mi = 0; mi < 2; ++mi)
#pragma unroll
    for (int ni = 0; ni < 2; ++ni) {
      const int cg = bn0 + n_off + ni * 16 + cl;
#pragma unroll
      for (int r = 0; r < 4; ++r) {
        const int rg = am0 + m_off + mi * 16 + rb + r;
        Cout[(size_t)rg * 512 + cg] = acc[mi][ni][r] + bias[cg];
      }
    }
}

// ---------------- launch ----------------
extern "C" void kernel_launch(void* const* d_in, const int* in_sizes, int n_in,
                              void* d_out, int out_size, void* d_ws, size_t ws_size,
                              hipStream_t stream) {
  const float* x      = (const float*)d_in[0];
  const float* w_qkv  = (const float*)d_in[1];
  const float* dwk    = (const float*)d_in[2];
  const float* abias  = (const float*)d_in[3];
  const float* pw     = (const float*)d_in[4];
  const float* pb     = (const float*)d_in[5];
  float* out = (float*)d_out;

  char* ws = (char*)d_ws;
  uint16_t* xb   = (uint16_t*)(ws);                 // 4 MB
  uint16_t* wqb  = (uint16_t*)(ws + (4ull << 20));  // 2 MB
  uint16_t* pwb  = (uint16_t*)(ws + (6ull << 20));  // 1 MB
  uint16_t* qT   = (uint16_t*)(ws + (7ull << 20));  // 4 MB  (transposed, pre-scaled)
  uint16_t* kbuf = (uint16_t*)(ws + (11ull << 20)); // 4 MB
  uint16_t* vimg = (uint16_t*)(ws + (15ull << 20)); // 8 MB  (later reused as hsO)
  uint16_t* vcv  = (uint16_t*)(ws + (23ull << 20)); // 8 MB  (channel-major = V^T)
  uint16_t* bt2b = (uint16_t*)(ws + (31ull << 20)); // 4 MB  bf16 bias tiles, C-layout
  uint16_t* hsO  = vimg;                            // alias: vimg dead after dwconv

  prep<<<5600, 256, 0, stream>>>(x, w_qkv, pw, abias, xb, wqb, pwb, bt2b);
  gemm_qkv<<<dim3(16, 32), 256, 0, stream>>>(xb, wqb, qT, kbuf, vimg);
  dwconv3x3<<<4096, 256, 0, stream>>>(vimg, dwk, vcv);
  attn_mfma<<<4096, 64, 0, stream>>>(qT, kbuf, vcv, bt2b, hsO);
  gemm_proj<<<dim3(8, 64), 256, 0, stream>>>(hsO, pwb, out, pb);
}